// Round 9
// baseline (126.047 us; speedup 1.0000x reference)
//
#include <hip/hip_runtime.h>
#include <hip/hip_bf16.h>
#include <math.h>

// Problem constants (B=16, T=3000, F=201)
constexpr int BB     = 16;
constexpr int T      = 3000;
constexpr int F      = 201;
constexpr int NFFT   = 400;
constexpr int HOP    = 160;
constexpr int K      = 402;            // 2*F real/imag interleaved
constexpr int ESTLEN = (T - 1) * HOP + NFFT;   // 480240
constexpr int OUTLEN = ESTLEN - NFFT;          // 479840 per batch
constexpr float EPS  = 1e-12f;

constexpr int NSTEP  = 26;             // k-steps of 16 (step 25 = k 400..415, mostly 0)
constexpr int NFRAG  = 13;             // j-frags: dt0:5, dt1:5, dt2:3
constexpr int UT     = 64;             // u-rows per wave/block
constexpr int AITEMS = 132;            // (UT+2 halo) rows x 2 16B-slots
constexpr int ABUF   = AITEMS * 8;     // shorts per A LDS buffer (2112 B)

typedef short bf16x8 __attribute__((ext_vector_type(8)));
typedef float f32x16 __attribute__((ext_vector_type(16)));

__device__ __forceinline__ unsigned short f2bf(float f) {
    unsigned int u = __float_as_uint(f);
    u = (u + 0x7fffu + ((u >> 16) & 1u)) >> 16;
    return (unsigned short)u;
}

// ---------------- table builders ----------------
// Fragment-linear W: Wg[(s*13+f)*512 + l*8 + e] = W[k][j], k = s*16+(l>>5)*8+e,
// j = jbase(f)+(l&31); jbase = dt*160+mf*32, f=(dt,mf). Zero if j>=400 or k>=402.
// W[k][j] = c_f * (re? cos : -sin)(2*pi*j*f/400) * win[j], f = k>>1.
__global__ void build_wt(unsigned short* __restrict__ Wg) {
    int idx = blockIdx.x * blockDim.x + threadIdx.x;
    if (idx >= NSTEP * NFRAG * 512) return;
    int fid = idx >> 9;
    int rem = idx & 511;
    int l = rem >> 3;
    int e = rem & 7;
    int s = fid / NFRAG;
    int f = fid - s * NFRAG;
    int dt = (f < 5) ? 0 : ((f < 10) ? 1 : 2);
    int mf = f - dt * 5;
    int j  = dt * 160 + mf * 32 + (l & 31);
    int k  = s * 16 + (l >> 5) * 8 + e;
    float v = 0.f;
    if (j < NFFT && k < K) {
        int fr = k >> 1;
        bool is_re = (k & 1) == 0;
        float c = (fr == 0 || fr == F - 1) ? (1.f / 400.f) : (2.f / 400.f);
        int m = (j * fr) % NFFT;
        float ang = (float)(2.0 * M_PI * (double)m / 400.0);
        float tw = is_re ? cosf(ang) : -sinf(ang);
        float win = 0.54f - 0.46f * cosf((float)(2.0 * M_PI * (double)j / 400.0));
        v = c * tw * win;
    }
    Wg[idx] = f2bf(v);
}

__global__ void build_rssw(float* __restrict__ rssw) {
    int p = blockIdx.x * blockDim.x + threadIdx.x;
    if (p >= ESTLEN) return;
    int t_hi = p / HOP; if (t_hi > T - 1) t_hi = T - 1;
    int t_lo = (p >= NFFT) ? ((p - NFFT) / HOP + 1) : 0;
    float s = 0.f;
    for (int t = t_lo; t <= t_hi; ++t) {
        int j = p - t * HOP;
        float w = 0.54f - 0.46f * cosf((float)(2.0 * M_PI * (double)j / 400.0));
        s += w * w;
    }
    rssw[p] = (s > EPS) ? 1.f / s : 1.f;
}

// ---------------- fused MFMA gather-GEMM: 1 wave per block, no barriers ------
// Wave tile: 64u x 160m. acc[2 ublk][5 mf] 32x32 frags. K: 26 steps of 16.
// W: direct global->reg dwordx4 per frag (L2-resident, fragment-linear table).
// A: fp32 global (coalesced 32B/row-half) -> bf16 -> tiny LDS dbuf (4224 B).
__global__ __launch_bounds__(64)
void istft_fused(const float* __restrict__ A, const unsigned short* __restrict__ Wg,
                 const float* __restrict__ rssw, const float* __restrict__ zpage,
                 float* __restrict__ out) {
    __shared__ __align__(16) unsigned short As[2 * ABUF];   // 4224 B

    const int lane = threadIdx.x;      // 0..63
    const int lj   = lane & 31;
    const int lh   = lane >> 5;
    const int b    = blockIdx.y;
    const int u0   = 1 + blockIdx.x * UT;
    const int tbase = u0 - 2;

    f32x16 acc[2][5];
    #pragma unroll
    for (int ub = 0; ub < 2; ++ub)
        #pragma unroll
        for (int mf = 0; mf < 5; ++mf)
            #pragma unroll
            for (int q = 0; q < 16; ++q) acc[ub][mf][q] = 0.f;

    // A staging: item = q*64+lane (q=2 only lane<4); row r = item>>1, half h = item&1.
    const int h = lane & 1;
    const float* rp[3];
    #pragma unroll
    for (int q = 0; q < 3; ++q) {
        int r = q * 32 + (lane >> 1);
        int t = tbase + r;
        rp[q] = (t >= 0 && t < T && r < 66) ? (A + (size_t)(b * T + t) * K) : zpage;
    }

    auto loadA = [&](int k0, float4* d) {
        if (k0 < 400) {
            #pragma unroll
            for (int q = 0; q < 3; ++q) {
                if (q < 2 || lane < 4) {
                    const float* s = rp[q] + k0 + h * 8;
                    d[q * 2]     = *reinterpret_cast<const float4*>(s);
                    d[q * 2 + 1] = *reinterpret_cast<const float4*>(s + 4);
                }
            }
        } else {   // tail: only k=400,401 real (k=401 column is 0 in W anyway)
            #pragma unroll
            for (int q = 0; q < 3; ++q) {
                if (q < 2 || lane < 4) {
                    float2 v = make_float2(0.f, 0.f);
                    if (h == 0) v = *reinterpret_cast<const float2*>(rp[q] + 400);
                    d[q * 2]     = make_float4(v.x, v.y, 0.f, 0.f);
                    d[q * 2 + 1] = make_float4(0.f, 0.f, 0.f, 0.f);
                }
            }
        }
    };

    auto writeA = [&](unsigned short* dst, const float4* d) {
        #pragma unroll
        for (int q = 0; q < 3; ++q) {
            if (q < 2 || lane < 4) {
                int item = q * 64 + lane;
                union { bf16x8 v; __hip_bfloat162 hh[4]; } u;
                u.hh[0] = __float22bfloat162_rn(make_float2(d[q*2].x,   d[q*2].y));
                u.hh[1] = __float22bfloat162_rn(make_float2(d[q*2].z,   d[q*2].w));
                u.hh[2] = __float22bfloat162_rn(make_float2(d[q*2+1].x, d[q*2+1].y));
                u.hh[3] = __float22bfloat162_rn(make_float2(d[q*2+1].z, d[q*2+1].w));
                *reinterpret_cast<bf16x8*>(&dst[item * 8]) = u.v;
            }
        }
    };

    // prologue: stage step 0
    {
        float4 d[6];
        loadA(0, d);
        writeA(As, d);
    }

    for (int s = 0; s < NSTEP; ++s) {
        const int cur = s & 1;
        float4 d[6];
        if (s + 1 < NSTEP) loadA((s + 1) * 16, d);   // issue early; lands under compute

        // W frags: direct global->reg, 1 KB coalesced each (L2-hit)
        const unsigned short* wb = Wg + ((size_t)(s * NFRAG) << 9) + lane * 8;
        bf16x8 wf[NFRAG];
        #pragma unroll
        for (int f = 0; f < NFRAG; ++f)
            wf[f] = *reinterpret_cast<const bf16x8*>(wb + ((size_t)f << 9));

        // A frags from LDS (contiguous 1KB reads: conflict-free)
        const unsigned short* Ab = As + cur * ABUF;
        bf16x8 af[2][3];
        #pragma unroll
        for (int ub = 0; ub < 2; ++ub)
            #pragma unroll
            for (int dt = 0; dt < 3; ++dt) {
                int row = ub * 32 + lj + 2 - dt;
                af[ub][dt] = *reinterpret_cast<const bf16x8*>(&Ab[(row * 2 + lh) * 8]);
            }

        // 26 MFMAs
        #pragma unroll
        for (int dt = 0; dt < 3; ++dt) {
            const int nmf = (dt < 2) ? 5 : 3;
            #pragma unroll
            for (int mf = 0; mf < 5; ++mf)
                if (mf < nmf)
                    #pragma unroll
                    for (int ub = 0; ub < 2; ++ub)
                        acc[ub][mf] = __builtin_amdgcn_mfma_f32_32x32x16_bf16(
                            af[ub][dt], wf[dt * 5 + mf], acc[ub][mf], 0, 0, 0);
        }

        if (s + 1 < NSTEP) writeA(As + (cur ^ 1) * ABUF, d);  // write late (other buf)
        // single wave: DS ops in-order, no barrier needed
    }

    // epilogue: normalized stores; every output owned by exactly one block
    #pragma unroll
    for (int ub = 0; ub < 2; ++ub)
        #pragma unroll
        for (int mf = 0; mf < 5; ++mf) {
            int m = mf * 32 + lj;
            #pragma unroll
            for (int rg = 0; rg < 16; ++rg) {
                int u  = u0 + ub * 32 + (rg & 3) + 8 * (rg >> 2) + 4 * lh;
                int pe = u * HOP + m;
                int po = pe - (NFFT / 2);
                if (po >= 0 && po < OUTLEN)
                    out[(size_t)b * OUTLEN + po] = acc[ub][mf][rg] * rssw[pe];
            }
        }
}

// ---------------- launcher ----------------
extern "C" void kernel_launch(void* const* d_in, const int* in_sizes, int n_in,
                              void* d_out, int out_size, void* d_ws, size_t ws_size,
                              hipStream_t stream) {
    const float* x = (const float*)d_in[0];
    float* out = (float*)d_out;

    char* ws = (char*)d_ws;
    unsigned short* Wg = (unsigned short*)ws;            // 26*13*512*2 = 346,112 B
    float* rssw  = (float*)(ws + 346112);                // ESTLEN floats = 1,920,960 B
    float* zpage = (float*)(ws + 346112 + 1920960);      // 2048 B zeros

    hipMemsetAsync(zpage, 0, 2048, stream);
    {
        int total = NSTEP * NFRAG * 512;                 // 173,056
        build_wt<<<(total + 255) / 256, 256, 0, stream>>>(Wg);
    }
    {
        build_rssw<<<(ESTLEN + 255) / 256, 256, 0, stream>>>(rssw);
    }
    {
        dim3 grid((T + UT - 1) / UT, BB);                // 47 x 16 = 752 blocks, 64 thr
        istft_fused<<<grid, 64, 0, stream>>>(x, Wg, rssw, zpage, out);
    }
}

// Round 10
// 95.516 us; speedup vs baseline: 1.3197x; 1.3197x over previous
//
#include <hip/hip_runtime.h>
#include <hip/hip_bf16.h>
#include <math.h>

// Problem constants (B=16, T=3000, F=201)
constexpr int BB     = 16;
constexpr int T      = 3000;
constexpr int F      = 201;
constexpr int NFFT   = 400;
constexpr int HOP    = 160;
constexpr int K      = 402;            // 2*F real/imag interleaved
constexpr int ESTLEN = (T - 1) * HOP + NFFT;   // 480240
constexpr int OUTLEN = ESTLEN - NFFT;          // 479840 per batch
constexpr float EPS  = 1e-12f;

constexpr int NSTEP  = 26;             // k-steps of 16 (step 25 = k 400.., mostly 0)
constexpr int NSTEPH = 13;             // steps per k-half wave
constexpr int NFRAG  = 13;             // j-frags: dt0:5, dt1:5, dt2:3
constexpr int UT     = 32;             // u-rows per wave tile
constexpr int AROWS  = 34;             // UT + 2 halo
constexpr int ABUFSH = AROWS * 16;     // shorts per A buffer (1088 B)

typedef short bf16x8 __attribute__((ext_vector_type(8)));
typedef float f32x16 __attribute__((ext_vector_type(16)));

__device__ __forceinline__ unsigned short f2bf(float f) {
    unsigned int u = __float_as_uint(f);
    u = (u + 0x7fffu + ((u >> 16) & 1u)) >> 16;
    return (unsigned short)u;
}

// ---------------- table builders (identical to r9, verified) ----------------
// Fragment-linear W: Wg[(s*13+f)*512 + l*8 + e] = W[k][j], k = s*16+(l>>5)*8+e,
// j = jbase(f)+(l&31); jbase = dt*160+mf*32. Zero if j>=400 or k>=402.
__global__ void build_wt(unsigned short* __restrict__ Wg) {
    int idx = blockIdx.x * blockDim.x + threadIdx.x;
    if (idx >= NSTEP * NFRAG * 512) return;
    int fid = idx >> 9;
    int rem = idx & 511;
    int l = rem >> 3;
    int e = rem & 7;
    int s = fid / NFRAG;
    int f = fid - s * NFRAG;
    int dt = (f < 5) ? 0 : ((f < 10) ? 1 : 2);
    int mf = f - dt * 5;
    int j  = dt * 160 + mf * 32 + (l & 31);
    int k  = s * 16 + (l >> 5) * 8 + e;
    float v = 0.f;
    if (j < NFFT && k < K) {
        int fr = k >> 1;
        bool is_re = (k & 1) == 0;
        float c = (fr == 0 || fr == F - 1) ? (1.f / 400.f) : (2.f / 400.f);
        int m = (j * fr) % NFFT;
        float ang = (float)(2.0 * M_PI * (double)m / 400.0);
        float tw = is_re ? cosf(ang) : -sinf(ang);
        float win = 0.54f - 0.46f * cosf((float)(2.0 * M_PI * (double)j / 400.0));
        v = c * tw * win;
    }
    Wg[idx] = f2bf(v);
}

__global__ void build_rssw(float* __restrict__ rssw) {
    int p = blockIdx.x * blockDim.x + threadIdx.x;
    if (p >= ESTLEN) return;
    int t_hi = p / HOP; if (t_hi > T - 1) t_hi = T - 1;
    int t_lo = (p >= NFFT) ? ((p - NFFT) / HOP + 1) : 0;
    float s = 0.f;
    for (int t = t_lo; t <= t_hi; ++t) {
        int j = p - t * HOP;
        float w = 0.54f - 0.46f * cosf((float)(2.0 * M_PI * (double)j / 400.0));
        s += w * w;
    }
    rssw[p] = (s > EPS) ? 1.f / s : 1.f;
}

// ---------------- fused MFMA gather-GEMM: k-split wave pairs, no loop barriers
// Block 128 thr = 2 waves (kh 0/1). Per wave: 32u x 160m x K-half, 13 steps.
// W: direct global->reg (L2-resident frag-linear table, 1KB coalesced loads).
// A: coalesced global -> bf16 -> tiny private LDS dbuf (conflict-free).
__global__ __launch_bounds__(128, 3)
void istft_fused(const float* __restrict__ A, const unsigned short* __restrict__ Wg,
                 const float* __restrict__ rssw, const float* __restrict__ zpage,
                 float* __restrict__ out) {
    __shared__ __align__(16) unsigned short AsAll[2 * 2 * ABUFSH];  // 4352 B
    __shared__ __align__(16) float xch[64 * 84];                    // 21504 B

    const int tid  = threadIdx.x;
    const int lane = tid & 63;
    const int kh   = tid >> 6;         // wave 0/1 = k-half
    const int lj   = lane & 31;
    const int lh   = lane >> 5;
    const int b    = blockIdx.y;
    const int u0   = 1 + blockIdx.x * UT;
    const int tbase = u0 - 2;
    const int base = kh * NSTEPH;      // first k-step of this wave

    unsigned short* As = AsAll + kh * 2 * ABUFSH;   // per-wave private buffers

    f32x16 acc[5];
    #pragma unroll
    for (int mf = 0; mf < 5; ++mf)
        #pragma unroll
        for (int q = 0; q < 16; ++q) acc[mf][q] = 0.f;

    // ---- A staging geometry: 136 16B-items; item = q*64+lane (q2: lane<8) ----
    // item -> row r = item>>2, chunk c = item&3 (floats k0+4c..k0+4c+3)
    const int c4 = (lane & 3) * 4;
    const float* rp[3];
    #pragma unroll
    for (int q = 0; q < 3; ++q) {
        int r = q * 16 + (lane >> 2);
        int t = tbase + r;
        rp[q] = (t >= 0 && t < T && r < AROWS) ? (A + (size_t)(b * T + t) * K) : zpage;
    }

    auto loadA = [&](int s, float4* d) {
        int k0 = s * 16;
        if (k0 < 400) {
            #pragma unroll
            for (int q = 0; q < 3; ++q)
                if (q < 2 || lane < 8)
                    d[q] = *reinterpret_cast<const float4*>(rp[q] + k0 + c4);
        } else {           // tail step 25: only k=400,401 exist
            #pragma unroll
            for (int q = 0; q < 3; ++q)
                if (q < 2 || lane < 8) {
                    float2 v = make_float2(0.f, 0.f);
                    if ((lane & 3) == 0) v = *reinterpret_cast<const float2*>(rp[q] + 400);
                    d[q] = make_float4(v.x, v.y, 0.f, 0.f);
                }
        }
    };

    auto writeA = [&](unsigned short* dst, const float4* d) {
        #pragma unroll
        for (int q = 0; q < 3; ++q)
            if (q < 2 || lane < 8) {
                int item = q * 64 + lane;
                __hip_bfloat162 h0 = __float22bfloat162_rn(make_float2(d[q].x, d[q].y));
                __hip_bfloat162 h1 = __float22bfloat162_rn(make_float2(d[q].z, d[q].w));
                union { uint2 u; __hip_bfloat162 h[2]; } pk;
                pk.h[0] = h0; pk.h[1] = h1;
                *reinterpret_cast<uint2*>(&dst[item * 4]) = pk.u;   // 8B linear
            }
    };

    // ---- prologue: stage step base into buf0; issue loads for base+1 ----
    float4 dA0[3], dA1[3];
    loadA(base, dA0);
    writeA(As, dA0);                   // buf 0 holds step base
    loadA(base + 1, dA1);              // in flight for step base+1

    // ---- main loop: no barriers (single-wave ordering) ----
    #pragma unroll
    for (int ii = 0; ii < NSTEPH; ++ii) {
        const int s = base + ii;

        // 1) W frags for this step: 13 coalesced 1KB loads (L2)
        const unsigned short* wb = Wg + ((size_t)(s * NFRAG) << 9) + lane * 8;
        bf16x8 wf[NFRAG];
        #pragma unroll
        for (int f = 0; f < NFRAG; ++f)
            wf[f] = *reinterpret_cast<const bf16x8*>(wb + ((size_t)f << 9));

        // 2) issue A loads for step s+2 (2-step slack for HBM latency)
        float4* dNew = (ii & 1) ? dA1 : dA0;   // buffer holding s+1 is the OTHER one
        float4* dOld = (ii & 1) ? dA0 : dA1;
        if (ii + 2 < NSTEPH) loadA(s + 2, dNew);

        // 3) write step s+1 data (loaded >=1 full step ago; cheap vmcnt)
        if (ii + 1 < NSTEPH) writeA(As + (((ii + 1) & 1) * ABUFSH), dOld);

        // 4) A frags from LDS buf[ii&1] (contiguous 1KB reads: conflict-free)
        const unsigned short* Ab = As + (ii & 1) * ABUFSH;
        bf16x8 af[3];
        #pragma unroll
        for (int dt = 0; dt < 3; ++dt) {
            int row = lj + 2 - dt;
            af[dt] = *reinterpret_cast<const bf16x8*>(&Ab[row * 16 + lh * 8]);
        }

        // 5) 13 MFMAs (waits only W loads; A loads still in flight)
        #pragma unroll
        for (int dt = 0; dt < 3; ++dt) {
            const int nmf = (dt < 2) ? 5 : 3;
            #pragma unroll
            for (int mf = 0; mf < 5; ++mf)
                if (mf < nmf)
                    acc[mf] = __builtin_amdgcn_mfma_f32_32x32x16_bf16(
                        af[dt], wf[dt * 5 + mf], acc[mf], 0, 0, 0);
        }
    }

    // ---- kh reduction (single barrier) + normalized stores ----
    if (kh == 1) {
        #pragma unroll
        for (int mf = 0; mf < 5; ++mf)
            #pragma unroll
            for (int q = 0; q < 4; ++q)
                *reinterpret_cast<float4*>(&xch[lane * 84 + mf * 16 + q * 4]) =
                    make_float4(acc[mf][q * 4], acc[mf][q * 4 + 1],
                                acc[mf][q * 4 + 2], acc[mf][q * 4 + 3]);
    }
    __syncthreads();
    if (kh == 0) {
        #pragma unroll
        for (int mf = 0; mf < 5; ++mf) {
            float part[16];
            #pragma unroll
            for (int q = 0; q < 4; ++q) {
                float4 v = *reinterpret_cast<const float4*>(&xch[lane * 84 + mf * 16 + q * 4]);
                part[q * 4] = v.x; part[q * 4 + 1] = v.y;
                part[q * 4 + 2] = v.z; part[q * 4 + 3] = v.w;
            }
            int m = mf * 32 + lj;
            #pragma unroll
            for (int rg = 0; rg < 16; ++rg) {
                int u  = u0 + (rg & 3) + 8 * (rg >> 2) + 4 * lh;
                int pe = u * HOP + m;
                int po = pe - (NFFT / 2);
                if (po >= 0 && po < OUTLEN)
                    out[(size_t)b * OUTLEN + po] = (acc[mf][rg] + part[rg]) * rssw[pe];
            }
        }
    }
}

// ---------------- launcher ----------------
extern "C" void kernel_launch(void* const* d_in, const int* in_sizes, int n_in,
                              void* d_out, int out_size, void* d_ws, size_t ws_size,
                              hipStream_t stream) {
    const float* x = (const float*)d_in[0];
    float* out = (float*)d_out;

    char* ws = (char*)d_ws;
    unsigned short* Wg = (unsigned short*)ws;            // 346,112 B
    float* rssw  = (float*)(ws + 346112);                // 1,920,960 B
    float* zpage = (float*)(ws + 346112 + 1920960);      // 2048 B zeros

    hipMemsetAsync(zpage, 0, 2048, stream);
    {
        int total = NSTEP * NFRAG * 512;                 // 173,056
        build_wt<<<(total + 255) / 256, 256, 0, stream>>>(Wg);
    }
    {
        build_rssw<<<(ESTLEN + 255) / 256, 256, 0, stream>>>(rssw);
    }
    {
        dim3 grid((T + UT - 1) / UT, BB);                // 94 x 16 = 1504 blocks
        istft_fused<<<grid, 128, 0, stream>>>(x, Wg, rssw, zpage, out);
    }
}